// Round 11
// baseline (224.939 us; speedup 1.0000x reference)
//
#include <hip/hip_runtime.h>
#include <hip/hip_fp16.h>
#include <math.h>

// Model: review-based recommender. ALL float tensors fp32.
// Shapes: VOCAB=20000, D=100, H=100, K=3, N_U=N_I=256, R=8, S=52, Sp=50, E=20000.
// Outputs (fp32, flat): pred_r[20000] @0, pred_c[20000] @20000,
//                       z_u[102400] @40000, z_i[102400] @142400.
//
// R11: (a) emb table pre-converted to f16 (k_prep) -> gather bytes halved,
// single f16 MFMA per (kt,nt) (no lo-term; X and W errors both 2^-11,
// logit rms ~3.4e-5 << margin 4e-4). LDS 23.5KB -> 6 blocks/CU.
// (b) k_edge replaced by dense G precompute (G_u[i][j]=Pu[j].PsumI[i],
// fp32 dots, f16 store) + O(1)-per-edge k_edge2.

typedef __attribute__((ext_vector_type(8))) _Float16 half8;
typedef __attribute__((ext_vector_type(4))) float f32x4;

__device__ __forceinline__ float sigmoidf_(float x) { return 1.f / (1.f + expf(-x)); }
__device__ __forceinline__ ushort f2h(float x) {
    union { __half h; ushort u; } t; t.h = __float2half(x); return t.u;
}
__device__ __forceinline__ float h2f(ushort u) {
    union { __half h; ushort u; } t; t.u = u; return __half2float(t.h);
}

#define Z_MARGIN 4e-4f
#define FLAG_CAP 204800

// ---------------------------------------------------------------------------
// K0: prep: Wt[kk=300][h=100] fp32 (refine); fc2t[h][dd]; zero Psum;
// wpack f16 B-frag layout (verified r10); zero flag cnt; emb -> f16 table.
__global__ void k_prep(const float* __restrict__ conv_w, const float* __restrict__ fc_w2_w,
                       const float* __restrict__ emb,
                       float* __restrict__ Wt, float* __restrict__ fc2t,
                       float* __restrict__ Psum, ushort* __restrict__ wpack,
                       int* __restrict__ flag_cnt, ushort* __restrict__ emb16) {
    int idx = blockIdx.x * 256 + threadIdx.x;
    if (idx < 30000) {
        int kk = idx / 100, h = idx - kk * 100;
        Wt[idx] = conv_w[h * 300 + kk];
    } else if (idx < 40000) {
        int j = idx - 30000;
        int h = j / 100, dd = j - h * 100;
        fc2t[j] = fc_w2_w[dd * 100 + h];
    } else if (idx < 91200) {
        Psum[idx - 40000] = 0.f;
    } else if (idx < 127040) {
        int j = idx - 91200;                   // [0, 35840)
        int frag = j >> 9, within = j & 511;
        int l = within >> 3, jj = within & 7;
        int kt = frag / 7, nt = frag % 7;
        int kk = kt * 32 + ((l >> 4) << 3) + jj;
        int h  = nt * 16 + (l & 15);
        wpack[j] = (kk < 300 && h < 100) ? f2h(conv_w[h * 300 + kk]) : (ushort)0;
    } else if (idx == 127040) {
        *flag_cnt = 0;
    } else {
        int j = idx - 127041;
        if (j < 2000000) emb16[j] = f2h(emb[j]);
    }
}

// ---------------------------------------------------------------------------
// K1: one instance per block (grid 4096), 256 threads = 4 waves, wave = m-tile.
__global__ __launch_bounds__(256, 6)
void k_branch(const int* __restrict__ u_rev, const int* __restrict__ i_rev,
              const ushort* __restrict__ emb16, const ushort* __restrict__ wpack,
              const float* __restrict__ conv_b, const float* __restrict__ fc_w_w,
              const float* __restrict__ fc_w_b, const float* __restrict__ fc_w2_b,
              const float* __restrict__ fc2t, const float* __restrict__ h_r_w,
              const float* __restrict__ h_c_w,
              float* __restrict__ Pbuf, float* __restrict__ Psum,
              float* __restrict__ zdot, float* __restrict__ Pdot,
              float* __restrict__ z_out, int* __restrict__ flag_cnt,
              int* __restrict__ flag_list) {
    __shared__ __align__(16) char smem[23552];
    ushort* xw    = (ushort*)smem;                   // [6656] f16 X (zero-padded)
    ushort* wbuf  = (ushort*)(smem + 13312);         // [3584] one kt-chunk B-frags
    int*    s_tok = (int*)(smem + 20480);            // [52]
    float*  s_vmax= (float*)(smem + 20688);          // [4][100]
    float*  s_maxf= (float*)(smem + 22288);          // [100]
    float*  s_z   = (float*)(smem + 22688);          // [52]
    float*  s_lg  = (float*)(smem + 22896);          // [52]
    float*  s_P   = (float*)(smem + 23104);          // [100]

    const int tid = threadIdx.x, lane = tid & 63, w = tid >> 6;
    const int gi = blockIdx.x;
    const int branch = gi >> 11, inst = gi & 2047;

    // W kt=0 preload (448 uint4; thread covers tid and tid+256)
    const uint4* wp4 = (const uint4*)wpack;
    uint4* wbuf4 = (uint4*)wbuf;
    uint4 st0 = wp4[tid];
    uint4 st1; if (tid < 192) st1 = wp4[256 + tid];

    const int* rev = branch ? i_rev : u_rev;
    if (tid < 52) s_tok[tid] = rev[inst * 52 + tid];
    __syncthreads();

    // gather: 1300 uint2 (4 f16 each) across 256 threads, independent loads
    {
        const uint2* emb2 = (const uint2*)emb16;
        uint2 v[6];
#pragma unroll
        for (int k = 0; k < 6; k++) {
            int idx = tid + (k << 8);
            if (idx < 1300) {
                int s = idx / 25, c = idx - s * 25;
                v[k] = emb2[s_tok[s] * 25 + c];
            }
        }
#pragma unroll
        for (int k = 0; k < 6; k++) {
            int idx = tid + (k << 8);
            if (idx < 1300) *(uint2*)(xw + idx * 4) = v[k];
        }
        uint4 z4; z4.x = 0u; z4.y = 0u; z4.z = 0u; z4.w = 0u;
        for (int t2 = tid; t2 < 182; t2 += 256)      // zero [5200,6656) ushorts
            ((uint4*)xw)[650 + t2] = z4;
    }

    // write kt=0 W chunk, preload kt=1
    wbuf4[tid] = st0;
    if (tid < 192) wbuf4[256 + tid] = st1;
    st0 = wp4[448 + tid];
    if (tid < 192) st1 = wp4[448 + 256 + tid];
    __syncthreads();

    f32x4 acc[7];
#pragma unroll
    for (int nt = 0; nt < 7; nt++) acc[nt] = (f32x4){0.f, 0.f, 0.f, 0.f};

    const int col = lane & 15, quad = lane >> 4, q8 = quad << 3;
    const int mt = w;

    for (int kt = 0; kt < 10; kt++) {
        {
            int e0 = (mt * 16 + col) * 100 + kt * 32 + q8;
            union AU { half8 h8; uint2 u2[2]; } a;
            a.u2[0] = *(const uint2*)(xw + e0);
            a.u2[1] = *(const uint2*)(xw + e0 + 4);
#pragma unroll
            for (int nt = 0; nt < 7; nt++) {
                union BU { half8 h8; uint4 u4; } b;
                b.u4 = wbuf4[nt * 64 + lane];
                acc[nt] = __builtin_amdgcn_mfma_f32_16x16x32_f16(a.h8, b.h8, acc[nt], 0, 0, 0);
            }
        }
        __syncthreads();                             // wbuf reads for kt done
        if (kt < 9) {
            wbuf4[tid] = st0;
            if (tid < 192) wbuf4[256 + tid] = st1;
            if (kt < 8) {
                st0 = wp4[(kt + 2) * 448 + tid];
                if (tid < 192) st1 = wp4[(kt + 2) * 448 + 256 + tid];
            }
            __syncthreads();                         // wbuf(kt+1) visible
        }
    }

    // --- epilogue. C/D layout: n=col, m-row = quad*4+j [r6-r10 verified].
    float cb[7], fw[7], vmax[7];
#pragma unroll
    for (int nt = 0; nt < 7; nt++) {
        int h = nt * 16 + col;
        cb[nt] = (h < 100) ? conv_b[h] : 0.f;
        fw[nt] = (h < 100) ? fc_w_w[h] : 0.f;
        vmax[nt] = 0.f;
    }
    const float fcb = fc_w_b[0];

#pragma unroll
    for (int j = 0; j < 4; j++) {
        int p = mt * 16 + quad * 4 + j;
        bool pv = p < 50;
        float part = 0.f;
#pragma unroll
        for (int nt = 0; nt < 7; nt++) {
            float c = acc[nt][j] + cb[nt];
            c = c > 0.f ? c : 0.f;
            part += c * fw[nt];
            if (pv) vmax[nt] = fmaxf(vmax[nt], c);
        }
        part += __shfl_xor(part, 1, 64);
        part += __shfl_xor(part, 2, 64);
        part += __shfl_xor(part, 4, 64);
        part += __shfl_xor(part, 8, 64);
        if (pv && col == 0) {
            float logit = part + fcb;
            float z = rintf(sigmoidf_(logit));
            s_z[p] = z;
            s_lg[p] = logit;
            z_out[branch * 102400 + inst * 50 + p] = z;
        }
    }

#pragma unroll
    for (int nt = 0; nt < 7; nt++) {
        float m = vmax[nt];
        m = fmaxf(m, __shfl_xor(m, 16, 64));
        m = fmaxf(m, __shfl_xor(m, 32, 64));
        int h = nt * 16 + col;
        if (quad == 0 && h < 100) s_vmax[w * 100 + h] = m;
    }
    __syncthreads();

    if (tid < 100) {
        float mx = fmaxf(fmaxf(s_vmax[tid], s_vmax[100 + tid]),
                         fmaxf(s_vmax[200 + tid], s_vmax[300 + tid]));
        s_maxf[tid] = mx;
    }
    __syncthreads();

    // P matvec (chunk-unrolled, verified) + Psum atomic
    if (tid < 100) {
        float a = fc_w2_b[tid];
        for (int h0 = 0; h0 < 100; h0 += 10) {
            float wv[10], mxv[10];
#pragma unroll
            for (int t = 0; t < 10; t++) {
                wv[t] = fc2t[(h0 + t) * 100 + tid];
                mxv[t] = s_maxf[h0 + t];
            }
#pragma unroll
            for (int t = 0; t < 10; t++) a += mxv[t] * wv[t];
        }
        Pbuf[gi * 100 + tid] = a;
        s_P[tid] = a;
        atomicAdd(&Psum[(branch * 256 + (inst >> 3)) * 100 + tid], a);
    }
    __syncthreads();

    if (w == 0) {
        float v = (lane < 50) ? s_z[lane] * h_r_w[branch * 50 + lane] : 0.f;
        for (int s = 1; s < 64; s <<= 1) v += __shfl_xor(v, s, 64);
        if (lane == 0) zdot[gi] = v;
    } else if (w == 1) {
        float u = 0.f;
        if (lane < 50) u = s_P[lane] * h_c_w[branch * 100 + lane]
                         + s_P[lane + 50] * h_c_w[branch * 100 + lane + 50];
        for (int s = 1; s < 64; s <<= 1) u += __shfl_xor(u, s, 64);
        if (lane == 0) Pdot[gi] = u;
    } else if (w == 2) {
        float lg = 1e9f;
        if (lane < 50) lg = s_lg[lane];
        unsigned long long mb = __ballot(fabsf(lg) < Z_MARGIN);
        int cnt = __popcll(mb);
        int base = 0;
        if (lane == 0 && cnt) base = atomicAdd(flag_cnt, cnt);
        base = __shfl(base, 0, 64);
        if (fabsf(lg) < Z_MARGIN) {
            int rank = __popcll(mb & ((1ull << lane) - 1ull));
            int k = base + rank;
            if (k < FLAG_CAP) flag_list[k] = gi * 50 + lane;
        }
    }
}

// ---------------------------------------------------------------------------
// K2: exact fp32 recompute of flagged z-logits (r7-r10 verified).
__launch_bounds__(256)
__global__ void k_refine(const int* __restrict__ u_rev, const int* __restrict__ i_rev,
                         const float* __restrict__ emb, const float* __restrict__ Wt,
                         const float* __restrict__ conv_b, const float* __restrict__ fc_w_w,
                         const float* __restrict__ fc_w_b, const float* __restrict__ h_r_w,
                         const int* __restrict__ flag_cnt, const int* __restrict__ flag_list,
                         float* __restrict__ z_out, float* __restrict__ zdot) {
    int n = *flag_cnt; if (n > FLAG_CAP) n = FLAG_CAP;
    const int lane = threadIdx.x & 63;
    const int wid = (blockIdx.x * 256 + threadIdx.x) >> 6;
    const int nw = gridDim.x * 4;
    const bool hv = lane < 50;
    const float cb0 = hv ? conv_b[lane] : 0.f;
    const float cb1 = hv ? conv_b[lane + 50] : 0.f;
    const float fw0 = hv ? fc_w_w[lane] : 0.f;
    const float fw1 = hv ? fc_w_w[lane + 50] : 0.f;
    const float fcb = fc_w_b[0];

    for (int e0 = wid * 4; e0 < n; e0 += nw * 4) {
        int gi[4], pos[4];
        bool iv[4];
        float xr[4][5];
#pragma unroll
        for (int m = 0; m < 4; m++) {
            int e = e0 + m;
            iv[m] = e < n;
            int code = iv[m] ? flag_list[e] : 0;
            gi[m] = code / 50; pos[m] = code - gi[m] * 50;
            const int* rev = (gi[m] >> 11) ? i_rev : u_rev;
            int tb = (gi[m] & 2047) * 52 + pos[m];
            int t0 = rev[tb], t1 = rev[tb + 1], t2 = rev[tb + 2];
#pragma unroll
            for (int s = 0; s < 5; s++) {
                int k = s * 64 + lane;
                float v = 0.f;
                if (k < 300) {
                    int r = k / 100, dd = k - r * 100;
                    int t = (r == 0) ? t0 : ((r == 1) ? t1 : t2);
                    v = emb[t * 100 + dd];
                }
                xr[m][s] = v;
            }
        }
        float c0[4], c1[4];
#pragma unroll
        for (int m = 0; m < 4; m++) { c0[m] = cb0; c1[m] = cb1; }
#pragma unroll
        for (int s = 0; s < 5; s++) {
            const int dmax = (s < 4) ? 64 : 44;
#pragma unroll 4
            for (int d2 = 0; d2 < dmax; d2++) {
                int d = s * 64 + d2;
                float w0 = hv ? Wt[d * 100 + lane] : 0.f;
                float w1 = hv ? Wt[d * 100 + lane + 50] : 0.f;
#pragma unroll
                for (int m = 0; m < 4; m++) {
                    float x = __shfl(xr[m][s], d2, 64);
                    c0[m] += x * w0;
                    c1[m] += x * w1;
                }
            }
        }
#pragma unroll
        for (int m = 0; m < 4; m++) {
            float v = fmaxf(c0[m], 0.f) * fw0 + fmaxf(c1[m], 0.f) * fw1;
            for (int s = 1; s < 64; s <<= 1) v += __shfl_xor(v, s, 64);
            if (lane == 0 && iv[m]) {
                int branch = gi[m] >> 11, inst = gi[m] & 2047;
                float z = rintf(sigmoidf_(v + fcb));
                float old = z_out[branch * 102400 + inst * 50 + pos[m]];
                if (z != old) {
                    z_out[branch * 102400 + inst * 50 + pos[m]] = z;
                    atomicAdd(&zdot[gi[m]], (z - old) * h_r_w[branch * 50 + pos[m]]);
                }
            }
        }
    }
}

// ---------------------------------------------------------------------------
// K3: dense G precompute. Block b: side s=b>>8, i=b&255.
// G[s][i][j] = dot(Pbuf[s*2048+j], vec), vec = PsumI[i] (s=0) / PsumU[i] (s=1).
__launch_bounds__(256)
__global__ void k_gmat(const float* __restrict__ Pbuf, const float* __restrict__ Psum,
                       ushort* __restrict__ G) {
    __shared__ __align__(16) float sv[100];
    const int b = blockIdx.x, s = b >> 8, i = b & 255;
    const int tid = threadIdx.x, lane = tid & 63, w = tid >> 6;
    const float* vec = Psum + (s == 0 ? 25600 : 0) + i * 100;
    if (tid < 100) sv[tid] = vec[tid];
    __syncthreads();
    const int g = lane >> 2, q = lane & 3;
    const float4* rows4 = (const float4*)(Pbuf + s * 204800);
    const float4* sv4 = (const float4*)sv;
    for (int pass = 0; pass < 32; pass++) {
        int j = pass * 64 + w * 16 + g;
        float part = 0.f;
#pragma unroll
        for (int t = 0; t < 7; t++) {
            int c = q + 4 * t;
            if (c < 25) {
                float4 a = rows4[j * 25 + c], bb = sv4[c];
                part += a.x * bb.x + a.y * bb.y + a.z * bb.z + a.w * bb.w;
            }
        }
        part += __shfl_xor(part, 1, 64);
        part += __shfl_xor(part, 2, 64);
        if (q == 0) G[s * 524288 + i * 2048 + j] = f2h(part);
    }
}

// ---------------------------------------------------------------------------
// K4: per-edge, O(1) reads. 16 lanes/edge (8 user rows + 8 item rows).
__launch_bounds__(256)
__global__ void k_edge(const int* __restrict__ uid, const int* __restrict__ iid,
                       const ushort* __restrict__ G,
                       const float* __restrict__ zdot, const float* __restrict__ Pdot,
                       const float* __restrict__ user_bias, const float* __restrict__ item_bias,
                       const float* __restrict__ global_bias, float* __restrict__ out) {
    const int tid = threadIdx.x, lane = tid & 63, w = tid >> 6;
    const int e = blockIdx.x * 16 + w * 4 + (lane >> 4);
    const int r = lane & 15;
    int u = uid[e], i = iid[e];
    float gv, wr, wc;
    if (r < 8) {
        gv = h2f(G[i * 2048 + u * 8 + r]);
        wr = zdot[u * 8 + r]; wc = Pdot[u * 8 + r];
    } else {
        int a = r - 8;
        gv = h2f(G[524288 + u * 2048 + i * 8 + a]);
        wr = zdot[2048 + i * 8 + a]; wc = Pdot[2048 + i * 8 + a];
    }
    float sg = sigmoidf_(gv);
    float cr = sg * wr, cc = sg * wc;
    cr += __shfl_xor(cr, 1, 64); cc += __shfl_xor(cc, 1, 64);
    cr += __shfl_xor(cr, 2, 64); cc += __shfl_xor(cc, 2, 64);
    cr += __shfl_xor(cr, 4, 64); cc += __shfl_xor(cc, 4, 64);
    cr += __shfl_xor(cr, 8, 64); cc += __shfl_xor(cc, 8, 64);
    if (r == 0) {
        out[e] = cr + user_bias[u] + item_bias[i] + global_bias[0];
        out[20000 + e] = cc;
    }
}

// ---------------------------------------------------------------------------
extern "C" void kernel_launch(void* const* d_in, const int* in_sizes, int n_in,
                              void* d_out, int out_size, void* d_ws, size_t ws_size,
                              hipStream_t stream) {
    const int*   u_rev    = (const int*)d_in[0];
    const int*   i_rev    = (const int*)d_in[1];
    const int*   uid      = (const int*)d_in[2];
    const int*   iid      = (const int*)d_in[3];
    const float* emb      = (const float*)d_in[4];
    const float* conv_w   = (const float*)d_in[5];
    const float* conv_b   = (const float*)d_in[6];
    const float* fc_w_w   = (const float*)d_in[7];
    const float* fc_w_b   = (const float*)d_in[8];
    const float* fc_w2_w  = (const float*)d_in[9];
    const float* fc_w2_b  = (const float*)d_in[10];
    const float* h_r_w    = (const float*)d_in[11];
    const float* h_c_w    = (const float*)d_in[12];
    const float* user_b   = (const float*)d_in[13];
    const float* item_b   = (const float*)d_in[14];
    const float* global_b = (const float*)d_in[15];
    float* out = (float*)d_out;

    float*  ws    = (float*)d_ws;
    float*  Pbuf  = ws;                       // [409600]
    float*  Psum  = ws + 409600;              // [51200]
    float*  zdotb = ws + 460800;              // [4096]
    float*  Pdotb = ws + 464896;              // [4096]
    float*  Wt    = ws + 468992;              // [30000]
    float*  fc2t  = ws + 498992;              // [10000]
    ushort* wpack = (ushort*)(ws + 508992);   // [35840] f16
    int*    flagc = (int*)(ws + 526912);      // [1]
    int*    flist = (int*)(ws + 526916);      // [204800]
    ushort* emb16 = (ushort*)(ws + 731716);   // [2,000,000] f16
    ushort* Gbuf  = (ushort*)(ws + 1731716);  // [2][256][2048] f16

    hipLaunchKernelGGL(k_prep, dim3(8309), dim3(256), 0, stream,
                       conv_w, fc_w2_w, emb, Wt, fc2t, Psum, wpack, flagc, emb16);
    hipLaunchKernelGGL(k_branch, dim3(4096), dim3(256), 0, stream,
                       u_rev, i_rev, emb16, wpack, conv_b, fc_w_w, fc_w_b,
                       fc_w2_b, fc2t, h_r_w, h_c_w,
                       Pbuf, Psum, zdotb, Pdotb, out + 40000, flagc, flist);
    hipLaunchKernelGGL(k_refine, dim3(128), dim3(256), 0, stream,
                       u_rev, i_rev, emb, Wt, conv_b, fc_w_w, fc_w_b, h_r_w,
                       flagc, flist, out + 40000, zdotb);
    hipLaunchKernelGGL(k_gmat, dim3(512), dim3(256), 0, stream, Pbuf, Psum, Gbuf);
    hipLaunchKernelGGL(k_edge, dim3(1250), dim3(256), 0, stream,
                       uid, iid, Gbuf, zdotb, Pdotb,
                       user_b, item_b, global_b, out);
}

// Round 14
// 188.393 us; speedup vs baseline: 1.1940x; 1.1940x over previous
//
#include <hip/hip_runtime.h>
#include <hip/hip_fp16.h>
#include <math.h>

// Model: review-based recommender. ALL float tensors fp32.
// Shapes: VOCAB=20000, D=100, H=100, K=3, N_U=N_I=256, R=8, S=52, Sp=50, E=20000.
// Outputs (fp32, flat): pred_r[20000] @0, pred_c[20000] @20000,
//                       z_u[102400] @40000, z_i[102400] @142400.
//
// R14 == R12/R13 resubmit (both benches were broker/container infra failures;
// source audited for fault/hang paths — none; r11 established ws_size >= 9MB
// with identical layout):
// (a) k_refine Wt loads batched into register arrays (r11 measured: 47.6us
// at 3% occupancy = 600 serialized L2 loads x ~190cyc). (b) k_gmat grid
// 512 -> 4096 (j split 8x256). (c) k_prep emb->f16 conversion vectorized x4.
// k_branch/k_edge identical to r11.

typedef __attribute__((ext_vector_type(8))) _Float16 half8;
typedef __attribute__((ext_vector_type(4))) float f32x4;

__device__ __forceinline__ float sigmoidf_(float x) { return 1.f / (1.f + expf(-x)); }
__device__ __forceinline__ ushort f2h(float x) {
    union { __half h; ushort u; } t; t.h = __float2half(x); return t.u;
}
__device__ __forceinline__ float h2f(ushort u) {
    union { __half h; ushort u; } t; t.u = u; return __half2float(t.h);
}

#define Z_MARGIN 4e-4f
#define FLAG_CAP 204800

// ---------------------------------------------------------------------------
// K0: prep: Wt[kk=300][h=100] fp32 (refine); fc2t[h][dd]; zero Psum;
// wpack f16 B-frag layout (verified r10/r11); zero flag cnt; emb -> f16 (x4 vec).
__global__ void k_prep(const float* __restrict__ conv_w, const float* __restrict__ fc_w2_w,
                       const float* __restrict__ emb,
                       float* __restrict__ Wt, float* __restrict__ fc2t,
                       float* __restrict__ Psum, ushort* __restrict__ wpack,
                       int* __restrict__ flag_cnt, ushort* __restrict__ emb16) {
    int idx = blockIdx.x * 256 + threadIdx.x;
    if (idx < 30000) {
        int kk = idx / 100, h = idx - kk * 100;
        Wt[idx] = conv_w[h * 300 + kk];
    } else if (idx < 40000) {
        int j = idx - 30000;
        int h = j / 100, dd = j - h * 100;
        fc2t[j] = fc_w2_w[dd * 100 + h];
    } else if (idx < 91200) {
        Psum[idx - 40000] = 0.f;
    } else if (idx < 127040) {
        int j = idx - 91200;                   // [0, 35840)
        int frag = j >> 9, within = j & 511;
        int l = within >> 3, jj = within & 7;
        int kt = frag / 7, nt = frag % 7;
        int kk = kt * 32 + ((l >> 4) << 3) + jj;
        int h  = nt * 16 + (l & 15);
        wpack[j] = (kk < 300 && h < 100) ? f2h(conv_w[h * 300 + kk]) : (ushort)0;
    } else if (idx == 127040) {
        *flag_cnt = 0;
    } else {
        int j = idx - 127041;                  // [0, 500000) float4 groups
        if (j < 500000) {
            float4 v = ((const float4*)emb)[j];
            uint2 o;
            o.x = (unsigned)f2h(v.x) | ((unsigned)f2h(v.y) << 16);
            o.y = (unsigned)f2h(v.z) | ((unsigned)f2h(v.w) << 16);
            ((uint2*)emb16)[j] = o;
        }
    }
}

// ---------------------------------------------------------------------------
// K1: one instance per block (grid 4096), 256 threads = 4 waves, wave = m-tile.
// (identical to r11)
__global__ __launch_bounds__(256, 6)
void k_branch(const int* __restrict__ u_rev, const int* __restrict__ i_rev,
              const ushort* __restrict__ emb16, const ushort* __restrict__ wpack,
              const float* __restrict__ conv_b, const float* __restrict__ fc_w_w,
              const float* __restrict__ fc_w_b, const float* __restrict__ fc_w2_b,
              const float* __restrict__ fc2t, const float* __restrict__ h_r_w,
              const float* __restrict__ h_c_w,
              float* __restrict__ Pbuf, float* __restrict__ Psum,
              float* __restrict__ zdot, float* __restrict__ Pdot,
              float* __restrict__ z_out, int* __restrict__ flag_cnt,
              int* __restrict__ flag_list) {
    __shared__ __align__(16) char smem[23552];
    ushort* xw    = (ushort*)smem;                   // [6656] f16 X (zero-padded)
    ushort* wbuf  = (ushort*)(smem + 13312);         // [3584] one kt-chunk B-frags
    int*    s_tok = (int*)(smem + 20480);            // [52]
    float*  s_vmax= (float*)(smem + 20688);          // [4][100]
    float*  s_maxf= (float*)(smem + 22288);          // [100]
    float*  s_z   = (float*)(smem + 22688);          // [52]
    float*  s_lg  = (float*)(smem + 22896);          // [52]
    float*  s_P   = (float*)(smem + 23104);          // [100]

    const int tid = threadIdx.x, lane = tid & 63, w = tid >> 6;
    const int gi = blockIdx.x;
    const int branch = gi >> 11, inst = gi & 2047;

    const uint4* wp4 = (const uint4*)wpack;
    uint4* wbuf4 = (uint4*)wbuf;
    uint4 st0 = wp4[tid];
    uint4 st1; if (tid < 192) st1 = wp4[256 + tid];

    const int* rev = branch ? i_rev : u_rev;
    if (tid < 52) s_tok[tid] = rev[inst * 52 + tid];
    __syncthreads();

    {
        const uint2* emb2 = (const uint2*)emb16;
        uint2 v[6];
#pragma unroll
        for (int k = 0; k < 6; k++) {
            int idx = tid + (k << 8);
            if (idx < 1300) {
                int s = idx / 25, c = idx - s * 25;
                v[k] = emb2[s_tok[s] * 25 + c];
            }
        }
#pragma unroll
        for (int k = 0; k < 6; k++) {
            int idx = tid + (k << 8);
            if (idx < 1300) *(uint2*)(xw + idx * 4) = v[k];
        }
        uint4 z4; z4.x = 0u; z4.y = 0u; z4.z = 0u; z4.w = 0u;
        for (int t2 = tid; t2 < 182; t2 += 256)
            ((uint4*)xw)[650 + t2] = z4;
    }

    wbuf4[tid] = st0;
    if (tid < 192) wbuf4[256 + tid] = st1;
    st0 = wp4[448 + tid];
    if (tid < 192) st1 = wp4[448 + 256 + tid];
    __syncthreads();

    f32x4 acc[7];
#pragma unroll
    for (int nt = 0; nt < 7; nt++) acc[nt] = (f32x4){0.f, 0.f, 0.f, 0.f};

    const int col = lane & 15, quad = lane >> 4, q8 = quad << 3;
    const int mt = w;

    for (int kt = 0; kt < 10; kt++) {
        {
            int e0 = (mt * 16 + col) * 100 + kt * 32 + q8;
            union AU { half8 h8; uint2 u2[2]; } a;
            a.u2[0] = *(const uint2*)(xw + e0);
            a.u2[1] = *(const uint2*)(xw + e0 + 4);
#pragma unroll
            for (int nt = 0; nt < 7; nt++) {
                union BU { half8 h8; uint4 u4; } b;
                b.u4 = wbuf4[nt * 64 + lane];
                acc[nt] = __builtin_amdgcn_mfma_f32_16x16x32_f16(a.h8, b.h8, acc[nt], 0, 0, 0);
            }
        }
        __syncthreads();
        if (kt < 9) {
            wbuf4[tid] = st0;
            if (tid < 192) wbuf4[256 + tid] = st1;
            if (kt < 8) {
                st0 = wp4[(kt + 2) * 448 + tid];
                if (tid < 192) st1 = wp4[(kt + 2) * 448 + 256 + tid];
            }
            __syncthreads();
        }
    }

    // epilogue. C/D layout: n=col, m-row = quad*4+j [r6-r11 verified].
    float cb[7], fw[7], vmax[7];
#pragma unroll
    for (int nt = 0; nt < 7; nt++) {
        int h = nt * 16 + col;
        cb[nt] = (h < 100) ? conv_b[h] : 0.f;
        fw[nt] = (h < 100) ? fc_w_w[h] : 0.f;
        vmax[nt] = 0.f;
    }
    const float fcb = fc_w_b[0];

#pragma unroll
    for (int j = 0; j < 4; j++) {
        int p = mt * 16 + quad * 4 + j;
        bool pv = p < 50;
        float part = 0.f;
#pragma unroll
        for (int nt = 0; nt < 7; nt++) {
            float c = acc[nt][j] + cb[nt];
            c = c > 0.f ? c : 0.f;
            part += c * fw[nt];
            if (pv) vmax[nt] = fmaxf(vmax[nt], c);
        }
        part += __shfl_xor(part, 1, 64);
        part += __shfl_xor(part, 2, 64);
        part += __shfl_xor(part, 4, 64);
        part += __shfl_xor(part, 8, 64);
        if (pv && col == 0) {
            float logit = part + fcb;
            float z = rintf(sigmoidf_(logit));
            s_z[p] = z;
            s_lg[p] = logit;
            z_out[branch * 102400 + inst * 50 + p] = z;
        }
    }

#pragma unroll
    for (int nt = 0; nt < 7; nt++) {
        float m = vmax[nt];
        m = fmaxf(m, __shfl_xor(m, 16, 64));
        m = fmaxf(m, __shfl_xor(m, 32, 64));
        int h = nt * 16 + col;
        if (quad == 0 && h < 100) s_vmax[w * 100 + h] = m;
    }
    __syncthreads();

    if (tid < 100) {
        float mx = fmaxf(fmaxf(s_vmax[tid], s_vmax[100 + tid]),
                         fmaxf(s_vmax[200 + tid], s_vmax[300 + tid]));
        s_maxf[tid] = mx;
    }
    __syncthreads();

    if (tid < 100) {
        float a = fc_w2_b[tid];
        for (int h0 = 0; h0 < 100; h0 += 10) {
            float wv[10], mxv[10];
#pragma unroll
            for (int t = 0; t < 10; t++) {
                wv[t] = fc2t[(h0 + t) * 100 + tid];
                mxv[t] = s_maxf[h0 + t];
            }
#pragma unroll
            for (int t = 0; t < 10; t++) a += mxv[t] * wv[t];
        }
        Pbuf[gi * 100 + tid] = a;
        s_P[tid] = a;
        atomicAdd(&Psum[(branch * 256 + (inst >> 3)) * 100 + tid], a);
    }
    __syncthreads();

    if (w == 0) {
        float v = (lane < 50) ? s_z[lane] * h_r_w[branch * 50 + lane] : 0.f;
        for (int s = 1; s < 64; s <<= 1) v += __shfl_xor(v, s, 64);
        if (lane == 0) zdot[gi] = v;
    } else if (w == 1) {
        float u = 0.f;
        if (lane < 50) u = s_P[lane] * h_c_w[branch * 100 + lane]
                         + s_P[lane + 50] * h_c_w[branch * 100 + lane + 50];
        for (int s = 1; s < 64; s <<= 1) u += __shfl_xor(u, s, 64);
        if (lane == 0) Pdot[gi] = u;
    } else if (w == 2) {
        float lg = 1e9f;
        if (lane < 50) lg = s_lg[lane];
        unsigned long long mb = __ballot(fabsf(lg) < Z_MARGIN);
        int cnt = __popcll(mb);
        int base = 0;
        if (lane == 0 && cnt) base = atomicAdd(flag_cnt, cnt);
        base = __shfl(base, 0, 64);
        if (fabsf(lg) < Z_MARGIN) {
            int rank = __popcll(mb & ((1ull << lane) - 1ull));
            int k = base + rank;
            if (k < FLAG_CAP) flag_list[k] = gi * 50 + lane;
        }
    }
}

// ---------------------------------------------------------------------------
// K2: exact fp32 recompute of flagged z-logits. Wt loads batched 16-deep into
// register arrays (32 loads in flight) -> loads pipeline instead of
// serializing at ~190cyc each. Same ascending-d FMA order as r7-r11.
__launch_bounds__(256)
__global__ void k_refine(const int* __restrict__ u_rev, const int* __restrict__ i_rev,
                         const float* __restrict__ emb, const float* __restrict__ Wt,
                         const float* __restrict__ conv_b, const float* __restrict__ fc_w_w,
                         const float* __restrict__ fc_w_b, const float* __restrict__ h_r_w,
                         const int* __restrict__ flag_cnt, const int* __restrict__ flag_list,
                         float* __restrict__ z_out, float* __restrict__ zdot) {
    int n = *flag_cnt; if (n > FLAG_CAP) n = FLAG_CAP;
    const int lane = threadIdx.x & 63;
    const int wid = (blockIdx.x * 256 + threadIdx.x) >> 6;
    const int nw = gridDim.x * 4;
    const bool hv = lane < 50;
    const float cb0 = hv ? conv_b[lane] : 0.f;
    const float cb1 = hv ? conv_b[lane + 50] : 0.f;
    const float fw0 = hv ? fc_w_w[lane] : 0.f;
    const float fw1 = hv ? fc_w_w[lane + 50] : 0.f;
    const float fcb = fc_w_b[0];

    for (int e0 = wid * 4; e0 < n; e0 += nw * 4) {
        int gi[4], pos[4];
        bool iv[4];
        float xr[4][5];
#pragma unroll
        for (int m = 0; m < 4; m++) {
            int e = e0 + m;
            iv[m] = e < n;
            int code = iv[m] ? flag_list[e] : 0;
            gi[m] = code / 50; pos[m] = code - gi[m] * 50;
            const int* rev = (gi[m] >> 11) ? i_rev : u_rev;
            int tb = (gi[m] & 2047) * 52 + pos[m];
            int t0 = rev[tb], t1 = rev[tb + 1], t2 = rev[tb + 2];
#pragma unroll
            for (int s = 0; s < 5; s++) {
                int k = s * 64 + lane;
                float v = 0.f;
                if (k < 300) {
                    int r = k / 100, dd = k - r * 100;
                    int t = (r == 0) ? t0 : ((r == 1) ? t1 : t2);
                    v = emb[t * 100 + dd];
                }
                xr[m][s] = v;
            }
        }
        float c0[4], c1[4];
#pragma unroll
        for (int m = 0; m < 4; m++) { c0[m] = cb0; c1[m] = cb1; }
        for (int s = 0; s < 5; s++) {
            const int dmax = (s < 4) ? 64 : 44;
            for (int db = 0; db < dmax; db += 16) {
                const int cnt = (dmax - db < 16) ? (dmax - db) : 16;
                float w0a[16], w1a[16];
#pragma unroll
                for (int t = 0; t < 16; t++) {
                    int d = s * 64 + db + t;
                    bool on = (t < cnt) && hv;          // masked: OOB lanes load 0
                    w0a[t] = on ? Wt[d * 100 + lane] : 0.f;
                    w1a[t] = on ? Wt[d * 100 + lane + 50] : 0.f;
                }
#pragma unroll
                for (int t = 0; t < 16; t++) {          // w==0 beyond cnt -> adds 0
#pragma unroll
                    for (int m = 0; m < 4; m++) {
                        float x = __shfl(xr[m][s], db + t, 64);
                        c0[m] += x * w0a[t];
                        c1[m] += x * w1a[t];
                    }
                }
            }
        }
#pragma unroll
        for (int m = 0; m < 4; m++) {
            float v = fmaxf(c0[m], 0.f) * fw0 + fmaxf(c1[m], 0.f) * fw1;
            for (int s = 1; s < 64; s <<= 1) v += __shfl_xor(v, s, 64);
            if (lane == 0 && iv[m]) {
                int branch = gi[m] >> 11, inst = gi[m] & 2047;
                float z = rintf(sigmoidf_(v + fcb));
                float old = z_out[branch * 102400 + inst * 50 + pos[m]];
                if (z != old) {
                    z_out[branch * 102400 + inst * 50 + pos[m]] = z;
                    atomicAdd(&zdot[gi[m]], (z - old) * h_r_w[branch * 50 + pos[m]]);
                }
            }
        }
    }
}

// ---------------------------------------------------------------------------
// K3: dense G precompute, grid 4096. Block b: s=b>>11, i=(b>>3)&255, jc=b&7.
// G[s][i][j] = dot(Pbuf[s*2048+j], vec), j in [jc*256, jc*256+256).
__launch_bounds__(256)
__global__ void k_gmat(const float* __restrict__ Pbuf, const float* __restrict__ Psum,
                       ushort* __restrict__ G) {
    __shared__ __align__(16) float sv[100];
    const int b = blockIdx.x, s = b >> 11, i = (b >> 3) & 255, jc = b & 7;
    const int tid = threadIdx.x, lane = tid & 63, w = tid >> 6;
    const float* vec = Psum + (s == 0 ? 25600 : 0) + i * 100;
    if (tid < 100) sv[tid] = vec[tid];
    __syncthreads();
    const int g = lane >> 2, q = lane & 3;
    const float4* rows4 = (const float4*)(Pbuf + s * 204800);
    const float4* sv4 = (const float4*)sv;
    for (int pass = 0; pass < 4; pass++) {
        int j = jc * 256 + pass * 64 + w * 16 + g;
        float part = 0.f;
#pragma unroll
        for (int t = 0; t < 7; t++) {
            int c = q + 4 * t;
            if (c < 25) {
                float4 a = rows4[j * 25 + c], bb = sv4[c];
                part += a.x * bb.x + a.y * bb.y + a.z * bb.z + a.w * bb.w;
            }
        }
        part += __shfl_xor(part, 1, 64);
        part += __shfl_xor(part, 2, 64);
        if (q == 0) G[s * 524288 + i * 2048 + j] = f2h(part);
    }
}

// ---------------------------------------------------------------------------
// K4: per-edge, O(1) reads (identical to r11).
__launch_bounds__(256)
__global__ void k_edge(const int* __restrict__ uid, const int* __restrict__ iid,
                       const ushort* __restrict__ G,
                       const float* __restrict__ zdot, const float* __restrict__ Pdot,
                       const float* __restrict__ user_bias, const float* __restrict__ item_bias,
                       const float* __restrict__ global_bias, float* __restrict__ out) {
    const int tid = threadIdx.x, lane = tid & 63, w = tid >> 6;
    const int e = blockIdx.x * 16 + w * 4 + (lane >> 4);
    const int r = lane & 15;
    int u = uid[e], i = iid[e];
    float gv, wr, wc;
    if (r < 8) {
        gv = h2f(G[i * 2048 + u * 8 + r]);
        wr = zdot[u * 8 + r]; wc = Pdot[u * 8 + r];
    } else {
        int a = r - 8;
        gv = h2f(G[524288 + u * 2048 + i * 8 + a]);
        wr = zdot[2048 + i * 8 + a]; wc = Pdot[2048 + i * 8 + a];
    }
    float sg = sigmoidf_(gv);
    float cr = sg * wr, cc = sg * wc;
    cr += __shfl_xor(cr, 1, 64); cc += __shfl_xor(cc, 1, 64);
    cr += __shfl_xor(cr, 2, 64); cc += __shfl_xor(cc, 2, 64);
    cr += __shfl_xor(cr, 4, 64); cc += __shfl_xor(cc, 4, 64);
    cr += __shfl_xor(cr, 8, 64); cc += __shfl_xor(cc, 8, 64);
    if (r == 0) {
        out[e] = cr + user_bias[u] + item_bias[i] + global_bias[0];
        out[20000 + e] = cc;
    }
}

// ---------------------------------------------------------------------------
extern "C" void kernel_launch(void* const* d_in, const int* in_sizes, int n_in,
                              void* d_out, int out_size, void* d_ws, size_t ws_size,
                              hipStream_t stream) {
    const int*   u_rev    = (const int*)d_in[0];
    const int*   i_rev    = (const int*)d_in[1];
    const int*   uid      = (const int*)d_in[2];
    const int*   iid      = (const int*)d_in[3];
    const float* emb      = (const float*)d_in[4];
    const float* conv_w   = (const float*)d_in[5];
    const float* conv_b   = (const float*)d_in[6];
    const float* fc_w_w   = (const float*)d_in[7];
    const float* fc_w_b   = (const float*)d_in[8];
    const float* fc_w2_w  = (const float*)d_in[9];
    const float* fc_w2_b  = (const float*)d_in[10];
    const float* h_r_w    = (const float*)d_in[11];
    const float* h_c_w    = (const float*)d_in[12];
    const float* user_b   = (const float*)d_in[13];
    const float* item_b   = (const float*)d_in[14];
    const float* global_b = (const float*)d_in[15];
    float* out = (float*)d_out;

    float*  ws    = (float*)d_ws;
    float*  Pbuf  = ws;                       // [409600]
    float*  Psum  = ws + 409600;              // [51200]
    float*  zdotb = ws + 460800;              // [4096]
    float*  Pdotb = ws + 464896;              // [4096]
    float*  Wt    = ws + 468992;              // [30000]
    float*  fc2t  = ws + 498992;              // [10000]
    ushort* wpack = (ushort*)(ws + 508992);   // [35840] f16
    int*    flagc = (int*)(ws + 526912);      // [1]
    int*    flist = (int*)(ws + 526916);      // [204800]
    ushort* emb16 = (ushort*)(ws + 731716);   // [2,000,000] f16
    ushort* Gbuf  = (ushort*)(ws + 1731716);  // [2][256][2048] f16

    hipLaunchKernelGGL(k_prep, dim3(2450), dim3(256), 0, stream,
                       conv_w, fc_w2_w, emb, Wt, fc2t, Psum, wpack, flagc, emb16);
    hipLaunchKernelGGL(k_branch, dim3(4096), dim3(256), 0, stream,
                       u_rev, i_rev, emb16, wpack, conv_b, fc_w_w, fc_w_b,
                       fc_w2_b, fc2t, h_r_w, h_c_w,
                       Pbuf, Psum, zdotb, Pdotb, out + 40000, flagc, flist);
    hipLaunchKernelGGL(k_refine, dim3(128), dim3(256), 0, stream,
                       u_rev, i_rev, emb, Wt, conv_b, fc_w_w, fc_w_b, h_r_w,
                       flagc, flist, out + 40000, zdotb);
    hipLaunchKernelGGL(k_gmat, dim3(4096), dim3(256), 0, stream, Pbuf, Psum, Gbuf);
    hipLaunchKernelGGL(k_edge, dim3(1250), dim3(256), 0, stream,
                       uid, iid, Gbuf, zdotb, Pdotb,
                       user_b, item_b, global_b, out);
}